// Round 4
// baseline (2967.657 us; speedup 1.0000x reference)
//
#include <hip/hip_runtime.h>
#include <cmath>

// Problem: x (B,D,T) fp32, codebooks (L,K,D) fp32 -> out (B,D,T), indices (B,L,T)
constexpr int Bb = 32, Dd = 256, Tt = 2048, Ll = 8, Kk = 1024;
constexpr int VT = 64;            // rows (t-positions) per block
constexpr int ROWU = 264;         // padded row in ushorts (bf16) / floats (Rrow overlay)
constexpr int HALF_USH = 64 * ROWU;          // 16896 ushorts per hi/lo half (64 codes)
constexpr int TILE_BYTES = 2 * HALF_USH * 2; // 67584 B
constexpr int CHUNKS = TILE_BYTES / 16 / 64; // 66 chunks of 1 KB

typedef __attribute__((ext_vector_type(8))) short short8;
typedef __attribute__((ext_vector_type(16))) float f32x16;

__device__ __forceinline__ ushort f2bf(float x) {
    union { float f; uint32_t u; } v{x};
    uint32_t r = v.u + 0x7fffu + ((v.u >> 16) & 1u);   // RNE
    return (ushort)(r >> 16);
}
__device__ __forceinline__ float bf2f(ushort h) {
    union { uint32_t u; float f; } v{((uint32_t)h) << 16};
    return v.f;
}
// monotone float->uint map (total order preserved)
__device__ __forceinline__ uint fmap(float f) {
    uint b = __float_as_uint(f);
    return b ^ (0x80000000u | (uint)((int)b >> 31));
}
__device__ __forceinline__ float funmap(uint u) {
    uint b = (u & 0x80000000u) ? (u ^ 0x80000000u) : ~u;
    return __uint_as_float(b);
}
__device__ __forceinline__ void gl_lds16(const void* g, void* l) {
    __builtin_amdgcn_global_load_lds(
        (const __attribute__((address_space(1))) unsigned int*)g,
        (__attribute__((address_space(3))) unsigned int*)l, 16, 0, 0);
}

// ---------------------------------------------------------------------------
// Prep (unchanged from round 3): wnorm with round-1 arithmetic + bf16 hi/lo
// split of codebook into the padded tile-blocked layout (global == LDS layout).
__global__ void prep_kernel(const float* __restrict__ cb, float* __restrict__ wn,
                            ushort* __restrict__ sp) {
    const int code = blockIdx.x;
    const int lane = threadIdx.x;
    const int l = code >> 10, kk = code & 1023, kt = kk >> 6, kr = kk & 63;
    const float4 v = ((const float4*)(cb + (size_t)code * Dd))[lane];
    float s = v.x * v.x + v.y * v.y + v.z * v.z + v.w * v.w;
#pragma unroll
    for (int off = 32; off > 0; off >>= 1) s += __shfl_down(s, off, 64);
    if (lane == 0) wn[code] = s;

    float f[4] = {v.x, v.y, v.z, v.w};
    ushort hs[4], ls[4];
#pragma unroll
    for (int i = 0; i < 4; ++i) {
        hs[i] = f2bf(f[i]);
        ls[i] = f2bf(f[i] - bf2f(hs[i]));
    }
    ushort* base = sp + (size_t)(l * 16 + kt) * (2 * HALF_USH) + kr * ROWU + lane * 4;
    *(ushort4*)base               = make_ushort4(hs[0], hs[1], hs[2], hs[3]);
    *(ushort4*)(base + HALF_USH)  = make_ushort4(ls[0], ls[1], ls[2], ls[3]);
}

// ---------------------------------------------------------------------------
__launch_bounds__(256, 2)
__global__ void rvq_kernel(const float* __restrict__ x, const float* __restrict__ cb,
                           const float* __restrict__ wn, const ushort* __restrict__ sp,
                           float* __restrict__ out, float* __restrict__ oidx) {
    __shared__ __align__(16) ushort Btile[2 * HALF_USH];  // 67584 B (also Rrow overlay)
    __shared__ int    cnt[VT];
    __shared__ ushort cand[VT * 64];
    __shared__ ushort hist[Ll][VT];

    const int tid = threadIdx.x;
    const int w = tid >> 6, lane = tid & 63;
    const int n = lane & 31;          // MFMA m (A row) = n, and B col n
    const int h = lane >> 5;          // k-half within 16-k step
    const int rh = w >> 1;            // row half of the 64-row block
    const int ch = w & 1;             // code half of the 64-code k-tile
    const int b = blockIdx.x >> 5, t0 = (blockIdx.x & 31) * VT;
    const int row32 = 32 * rh + n;    // local row owned by this lane (A layout)
    const int t_a = t0 + row32;

    // Canonical residual = bf16 hi/lo A-fragments (32x32x16 layout):
    // element (t, j) = residual[row32][16t + 8h + j],  t=0..15, j=0..7.
    short8 ahf[16], alf[16];
    {
        const float* xb = x + (size_t)b * Dd * Tt + t_a;
#pragma unroll
        for (int t = 0; t < 16; ++t)
#pragma unroll
            for (int j = 0; j < 8; ++j) {
                float v = xb[(size_t)(16 * t + 8 * h + j) * Tt];
                ushort hi = f2bf(v);
                ahf[t][j] = (short)hi;
                alf[t][j] = (short)f2bf(v - bf2f(hi));
            }
    }

    for (int l = 0; l < Ll; ++l) {
        const float*  cbl = cb + (size_t)l * Kk * Dd;
        const float*  wnl = wn + l * Kk;
        const ushort* spl = sp + (size_t)l * 16 * (2 * HALF_USH);

        // per-C-element top-2 as sortable uint keys; low 4 bits carry kt
        uint u1[16], u2[16];
#pragma unroll
        for (int e = 0; e < 16; ++e) { u1[e] = 0xFFFFFFFFu; u2[e] = 0xFFFFFFFFu; }

        for (int kt = 0; kt < 16; ++kt) {
            __syncthreads();  // previous tile / Rrow readers done
            {   // stage hi+lo tile (flat 67584 B), wave-strided
                const char* gsrc = (const char*)spl + (size_t)kt * TILE_BYTES;
                char* ldst = (char*)Btile;
                for (int c2 = w; c2 < CHUNKS; c2 += 4)
                    gl_lds16(gsrc + c2 * 1024 + lane * 16, ldst + c2 * 1024);
            }
            __syncthreads();  // staging drained

            const float wnv = wnl[kt * 64 + ch * 32 + n];   // lane's single code col

            f32x16 hh = (f32x16)0.f, hl = (f32x16)0.f, lh = (f32x16)0.f;
#pragma unroll
            for (int t = 0; t < 16; ++t) {
                const ushort* bp = Btile + (ch * 32 + n) * ROWU + 16 * t + 8 * h;
                short8 bh = *(const short8*)bp;
                short8 bl = *(const short8*)(bp + HALF_USH);
                hh = __builtin_amdgcn_mfma_f32_32x32x16_bf16(ahf[t], bh, hh, 0, 0, 0);
                lh = __builtin_amdgcn_mfma_f32_32x32x16_bf16(alf[t], bh, lh, 0, 0, 0);
                hl = __builtin_amdgcn_mfma_f32_32x32x16_bf16(ahf[t], bl, hl, 0, 0, 0);
            }
#pragma unroll
            for (int e = 0; e < 16; ++e) {
                float dist = fmaf(-2.f, hh[e] + hl[e] + lh[e], wnv);  // rel distance
                uint key = (fmap(dist) & 0xFFFFFFF0u) | (uint)kt;
                uint mx = u1[e] > key ? u1[e] : key;
                u2[e] = u2[e] < mx ? u2[e] : mx;
                u1[e] = u1[e] < key ? u1[e] : key;
            }
        }

        // ---- candidate phase ----
        __syncthreads();                  // all Btile reads done
        if (tid < VT) cnt[tid] = 0;
        __syncthreads();

#pragma unroll
        for (int e = 0; e < 16; ++e) {
            const int rloc = (e & 3) + 8 * (e >> 2) + 4 * h;   // 32x32 C row mapping
            const int row = 32 * rh + rloc;
            uint bm = u1[e];
#pragma unroll
            for (int off = 1; off < 32; off <<= 1) {
                uint o = (uint)__shfl_xor((int)bm, off, 64);
                bm = o < bm ? o : bm;
            }
            const uint thr = fmap(funmap(bm) + 0.15f) | 0xFu;  // margin >> approx err
            if (u1[e] <= thr) {
                int s_ = atomicAdd(&cnt[row], 1);
                if (s_ < 64) cand[row * 64 + s_] = (ushort)((u1[e] & 15u) * 64 + ch * 32 + n);
            }
            if (u2[e] <= thr) {
                int s_ = atomicAdd(&cnt[row], 1);
                if (s_ < 64) cand[row * 64 + s_] = (ushort)((u2[e] & 15u) * 64 + ch * 32 + n);
            }
        }
        __syncthreads();

        // ---- selection: cnt==1 -> done; else exact fp32 rescore with
        // BIT-EXACT round-1 arithmetic on the reconstructed residual ----
        if (tid < VT) {
            const int row = tid;
            const int nc = cnt[row] < 64 ? cnt[row] : 64;
            int bi = cand[row * 64];
            if (nc > 1) {
                float* Rrow = (float*)Btile + row * ROWU;  // private 264-float slab
                const float* xrow = x + (size_t)b * Dd * Tt + t0 + row;
                for (int d = 0; d < Dd; ++d) Rrow[d] = xrow[(size_t)d * Tt];
                for (int j = 0; j < l; ++j) {              // numpy subtract order
                    const float* qp = cb + ((size_t)j * Kk + hist[j][row]) * Dd;
                    for (int d = 0; d < Dd; ++d) Rrow[d] -= qp[d];
                }
                float rn = 0.f;                             // round-1 rnorm expr
                for (int i = 0; i < Dd / 4; ++i) {
                    float4 r4 = *(const float4*)(Rrow + 4 * i);
                    rn += r4.x * r4.x + r4.y * r4.y + r4.z * r4.z + r4.w * r4.w;
                }
                float bd = __builtin_inff(); bi = 0x7fffffff;
                for (int c2 = 0; c2 < nc; ++c2) {
                    const int cc = cand[row * 64 + c2];
                    const float* wp = cbl + (size_t)cc * Dd;
                    float dot = 0.f;                        // ascending fmaf chain
                    for (int d = 0; d < Dd; ++d)
                        dot = fmaf(Rrow[d], wp[d], dot);
                    const float dist = (rn - 2.0f * dot) + wnl[cc];
                    if (dist < bd || (dist == bd && cc < bi)) { bd = dist; bi = cc; }
                }
            }
            hist[l][row] = (ushort)bi;
            oidx[((size_t)b * Ll + l) * Tt + t0 + row] = (float)bi;
        }
        __syncthreads();

        // ---- approx residual update: r~ <- (hi+lo) - q, re-split ----
        {
            const int cc = hist[l][row32];
            const float* wp = cbl + (size_t)cc * Dd;
#pragma unroll
            for (int t = 0; t < 16; ++t) {
                float4 q0 = *(const float4*)(wp + 16 * t + 8 * h);
                float4 q1 = *(const float4*)(wp + 16 * t + 8 * h + 4);
                float qv[8] = {q0.x, q0.y, q0.z, q0.w, q1.x, q1.y, q1.z, q1.w};
#pragma unroll
                for (int j = 0; j < 8; ++j) {
                    float v = (bf2f((ushort)ahf[t][j]) + bf2f((ushort)alf[t][j])) - qv[j];
                    ushort hi = f2bf(v);
                    ahf[t][j] = (short)hi;
                    alf[t][j] = (short)f2bf(v - bf2f(hi));
                }
            }
        }
    }

    // ---- final: exact residual chain (bit-identical to rounds 1/3) + out ----
    {
        const float* xb = x + (size_t)b * Dd * Tt + t_a;
        float* ob = out + (size_t)b * Dd * Tt + t_a;
#pragma unroll
        for (int t = 0; t < 16; ++t) {
            float xv[8], v[8];
#pragma unroll
            for (int j = 0; j < 8; ++j) {
                xv[j] = xb[(size_t)(16 * t + 8 * h + j) * Tt];
                v[j] = xv[j];
            }
            for (int lay = 0; lay < Ll; ++lay) {
                const float* qp = cb + ((size_t)lay * Kk + hist[lay][row32]) * Dd
                                  + 16 * t + 8 * h;
                float4 q0 = *(const float4*)qp;
                float4 q1 = *(const float4*)(qp + 4);
                v[0] -= q0.x; v[1] -= q0.y; v[2] -= q0.z; v[3] -= q0.w;
                v[4] -= q1.x; v[5] -= q1.y; v[6] -= q1.z; v[7] -= q1.w;
            }
#pragma unroll
            for (int j = 0; j < 8; ++j)
                ob[(size_t)(16 * t + 8 * h + j) * Tt] = xv[j] - v[j];
        }
    }
}

// ---------------------------------------------------------------------------
extern "C" void kernel_launch(void* const* d_in, const int* in_sizes, int n_in,
                              void* d_out, int out_size, void* d_ws, size_t ws_size,
                              hipStream_t stream) {
    const float* x  = (const float*)d_in[0];   // (B, D, T)
    const float* cb = (const float*)d_in[1];   // (L, K, D)
    float* out  = (float*)d_out;
    float* oidx = out + (size_t)Bb * Dd * Tt;  // (B, L, T) as fp32 values
    float*  wnbuf = (float*)d_ws;                          // 8192 floats
    ushort* spbuf = (ushort*)((char*)d_ws + 32768);        // split codebook, ~8.65 MB

    prep_kernel<<<Ll * Kk, 64, 0, stream>>>(cb, wnbuf, spbuf);
    rvq_kernel<<<(Bb * Tt) / VT, 256, 0, stream>>>(x, cb, wnbuf, spbuf, out, oidx);
}

// Round 5
// 2902.341 us; speedup vs baseline: 1.0225x; 1.0225x over previous
//
#include <hip/hip_runtime.h>
#include <cmath>

// Problem: x (B,D,T) fp32, codebooks (L,K,D) fp32 -> out (B,D,T), indices (B,L,T)
constexpr int Bb = 32, Dd = 256, Tt = 2048, Ll = 8, Kk = 1024;
constexpr int VT = 64;            // rows (t-positions) per block
constexpr int ROWU = 264;         // padded row in ushorts (bf16) / floats (Rrow overlay)
constexpr int HALF_USH = 64 * ROWU;          // 16896 ushorts per hi/lo half (64 codes)
constexpr int TILE_BYTES = 2 * HALF_USH * 2; // 67584 B
constexpr int CHUNKS = TILE_BYTES / 16 / 64; // 66 chunks of 1 KB

typedef __attribute__((ext_vector_type(8))) short short8;
typedef __attribute__((ext_vector_type(16))) float f32x16;

__device__ __forceinline__ ushort f2bf(float x) {
    union { float f; uint32_t u; } v{x};
    uint32_t r = v.u + 0x7fffu + ((v.u >> 16) & 1u);   // RNE
    return (ushort)(r >> 16);
}
__device__ __forceinline__ float bf2f(ushort h) {
    union { uint32_t u; float f; } v{((uint32_t)h) << 16};
    return v.f;
}
// monotone float->uint map (total order preserved)
__device__ __forceinline__ uint fmap(float f) {
    uint b = __float_as_uint(f);
    return b ^ (0x80000000u | (uint)((int)b >> 31));
}
__device__ __forceinline__ float funmap(uint u) {
    uint b = (u & 0x80000000u) ? (u ^ 0x80000000u) : ~u;
    return __uint_as_float(b);
}
__device__ __forceinline__ void gl_lds16(const void* g, void* l) {
    __builtin_amdgcn_global_load_lds(
        (const __attribute__((address_space(1))) unsigned int*)g,
        (__attribute__((address_space(3))) unsigned int*)l, 16, 0, 0);
}

// ---------------------------------------------------------------------------
// Prep: wnorm (round-1 arithmetic) + bf16 hi/lo split of codebook into the
// padded tile-blocked layout (global layout == LDS layout, flat copy).
__global__ void prep_kernel(const float* __restrict__ cb, float* __restrict__ wn,
                            ushort* __restrict__ sp) {
    const int code = blockIdx.x;
    const int lane = threadIdx.x;
    const int l = code >> 10, kk = code & 1023, kt = kk >> 6, kr = kk & 63;
    const float4 v = ((const float4*)(cb + (size_t)code * Dd))[lane];
    float s = v.x * v.x + v.y * v.y + v.z * v.z + v.w * v.w;
#pragma unroll
    for (int off = 32; off > 0; off >>= 1) s += __shfl_down(s, off, 64);
    if (lane == 0) wn[code] = s;

    float f[4] = {v.x, v.y, v.z, v.w};
    ushort hs[4], ls[4];
#pragma unroll
    for (int i = 0; i < 4; ++i) {
        hs[i] = f2bf(f[i]);
        ls[i] = f2bf(f[i] - bf2f(hs[i]));
    }
    ushort* base = sp + (size_t)(l * 16 + kt) * (2 * HALF_USH) + kr * ROWU + lane * 4;
    *(ushort4*)base               = make_ushort4(hs[0], hs[1], hs[2], hs[3]);
    *(ushort4*)(base + HALF_USH)  = make_ushort4(ls[0], ls[1], ls[2], ls[3]);
}

// ---------------------------------------------------------------------------
__launch_bounds__(256, 2)
__global__ void rvq_kernel(const float* __restrict__ x, const float* __restrict__ cb,
                           const float* __restrict__ wn, const ushort* __restrict__ sp,
                           float* __restrict__ out, float* __restrict__ oidx) {
    __shared__ __align__(16) ushort Btile[2 * HALF_USH];  // 67584 B (also Rrow overlay)
    __shared__ uint   rowmin[VT];
    __shared__ int    cnt[VT];
    __shared__ ushort cand[VT * 64];
    __shared__ ushort hist[Ll][VT];

    const int tid = threadIdx.x;
    const int w = tid >> 6, lane = tid & 63;
    const int n = lane & 31;          // MFMA m (A row) = n, and B col n
    const int h = lane >> 5;          // k-half within 16-k step
    const int rh = w >> 1;            // row half of the 64-row block
    const int ch = w & 1;             // code half of the 64-code k-tile
    const int b = blockIdx.x >> 5, t0 = (blockIdx.x & 31) * VT;
    const int row32 = 32 * rh + n;    // local row owned by this lane (A layout)
    const int t_a = t0 + row32;

    // Canonical residual = bf16 hi/lo A-fragments (32x32x16 layout):
    // element (t, j) = residual[row32][16t + 8h + j],  t=0..15, j=0..7.
    short8 ahf[16], alf[16];
    {
        const float* xb = x + (size_t)b * Dd * Tt + t_a;
#pragma unroll
        for (int t = 0; t < 16; ++t)
#pragma unroll
            for (int j = 0; j < 8; ++j) {
                float v = xb[(size_t)(16 * t + 8 * h + j) * Tt];
                ushort hi = f2bf(v);
                ahf[t][j] = (short)hi;
                alf[t][j] = (short)f2bf(v - bf2f(hi));
            }
    }

    for (int l = 0; l < Ll; ++l) {
        const float*  cbl = cb + (size_t)l * Kk * Dd;
        const float*  wnl = wn + l * Kk;
        const ushort* spl = sp + (size_t)l * 16 * (2 * HALF_USH);

        // per-C-element top-2 as sortable uint keys; low 4 bits carry kt
        uint u1[16], u2[16];
#pragma unroll
        for (int e = 0; e < 16; ++e) { u1[e] = 0xFFFFFFFFu; u2[e] = 0xFFFFFFFFu; }
        if (tid < VT) { cnt[tid] = 0; rowmin[tid] = 0xFFFFFFFFu; }

        for (int kt = 0; kt < 16; ++kt) {
            __syncthreads();  // previous tile / Rrow readers done (+ cnt zero visible)
            {   // stage hi+lo tile (flat 67584 B), wave-strided
                const char* gsrc = (const char*)spl + (size_t)kt * TILE_BYTES;
                char* ldst = (char*)Btile;
                for (int c2 = w; c2 < CHUNKS; c2 += 4)
                    gl_lds16(gsrc + c2 * 1024 + lane * 16, ldst + c2 * 1024);
            }
            __syncthreads();  // staging drained

            const float wnv = wnl[kt * 64 + ch * 32 + n];   // lane's single code col

            // two accumulator chains (32 regs total): accA <- ah*bh + ah*bl,
            // accB <- al*bh. Chained fp32 accumulate is fine (approx distance).
            f32x16 accA = (f32x16)0.f, accB = (f32x16)0.f;
#pragma unroll
            for (int t = 0; t < 16; ++t) {
                const ushort* bp = Btile + (ch * 32 + n) * ROWU + 16 * t + 8 * h;
                short8 bh = *(const short8*)bp;
                short8 bl = *(const short8*)(bp + HALF_USH);
                accA = __builtin_amdgcn_mfma_f32_32x32x16_bf16(ahf[t], bh, accA, 0, 0, 0);
                accB = __builtin_amdgcn_mfma_f32_32x32x16_bf16(alf[t], bh, accB, 0, 0, 0);
                accA = __builtin_amdgcn_mfma_f32_32x32x16_bf16(ahf[t], bl, accA, 0, 0, 0);
            }
#pragma unroll
            for (int e = 0; e < 16; ++e) {
                float dist = fmaf(-2.f, accA[e] + accB[e], wnv);  // rel distance
                uint key = (fmap(dist) & 0xFFFFFFF0u) | (uint)kt;
                uint mx = u1[e] > key ? u1[e] : key;
                u2[e] = u2[e] < mx ? u2[e] : mx;
                u1[e] = u1[e] < key ? u1[e] : key;
            }
        }

        // ---- GLOBAL per-row min across all 64 chains (both waves) ----
#pragma unroll
        for (int e = 0; e < 16; ++e) {
            const int row = 32 * rh + ((e & 3) + 8 * (e >> 2) + 4 * h);
            atomicMin(&rowmin[row], u1[e]);
        }
        __syncthreads();

        // margin filter vs GLOBAL row min -> cnt==1 for almost every row
#pragma unroll
        for (int e = 0; e < 16; ++e) {
            const int row = 32 * rh + ((e & 3) + 8 * (e >> 2) + 4 * h);
            const uint thr = fmap(funmap(rowmin[row]) + 0.15f) | 0xFu;
            if (u1[e] <= thr) {
                int s_ = atomicAdd(&cnt[row], 1);
                if (s_ < 64) cand[row * 64 + s_] = (ushort)((u1[e] & 15u) * 64 + ch * 32 + n);
            }
            if (u2[e] <= thr) {
                int s_ = atomicAdd(&cnt[row], 1);
                if (s_ < 64) cand[row * 64 + s_] = (ushort)((u2[e] & 15u) * 64 + ch * 32 + n);
            }
        }
        __syncthreads();

        // ---- selection: cnt==1 -> done; else exact fp32 rescore with
        // BIT-EXACT round-1 arithmetic on the reconstructed residual ----
        if (tid < VT) {
            const int row = tid;
            const int nc = cnt[row] < 64 ? cnt[row] : 64;
            int bi = cand[row * 64];
            if (nc > 1) {
                float* Rrow = (float*)Btile + row * ROWU;  // private 264-float slab
                const float* xrow = x + (size_t)b * Dd * Tt + t0 + row;
#pragma unroll 4
                for (int d = 0; d < Dd; ++d) Rrow[d] = xrow[(size_t)d * Tt];
                for (int j = 0; j < l; ++j) {              // numpy subtract order
                    const float* qp = cb + ((size_t)j * Kk + hist[j][row]) * Dd;
#pragma unroll 4
                    for (int d = 0; d < Dd; ++d) Rrow[d] -= qp[d];
                }
                float rn = 0.f;                             // round-1 rnorm expr
#pragma unroll 4
                for (int i = 0; i < Dd / 4; ++i) {
                    float4 r4 = *(const float4*)(Rrow + 4 * i);
                    rn += r4.x * r4.x + r4.y * r4.y + r4.z * r4.z + r4.w * r4.w;
                }
                float bd = __builtin_inff(); bi = 0x7fffffff;
                for (int c2 = 0; c2 < nc; ++c2) {
                    const int cc = cand[row * 64 + c2];
                    const float* wp = cbl + (size_t)cc * Dd;
                    float dot = 0.f;                        // ascending fmaf chain
#pragma unroll 4
                    for (int d = 0; d < Dd; ++d)
                        dot = fmaf(Rrow[d], wp[d], dot);
                    const float dist = (rn - 2.0f * dot) + wnl[cc];
                    if (dist < bd || (dist == bd && cc < bi)) { bd = dist; bi = cc; }
                }
            }
            hist[l][row] = (ushort)bi;
            oidx[((size_t)b * Ll + l) * Tt + t0 + row] = (float)bi;
        }
        __syncthreads();

        // ---- approx residual update: r~ <- (hi+lo) - q, re-split ----
        {
            const int cc = hist[l][row32];
            const float* wp = cbl + (size_t)cc * Dd;
#pragma unroll
            for (int t = 0; t < 16; ++t) {
                float4 q0 = *(const float4*)(wp + 16 * t + 8 * h);
                float4 q1 = *(const float4*)(wp + 16 * t + 8 * h + 4);
                float qv[8] = {q0.x, q0.y, q0.z, q0.w, q1.x, q1.y, q1.z, q1.w};
#pragma unroll
                for (int j = 0; j < 8; ++j) {
                    float v = (bf2f((ushort)ahf[t][j]) + bf2f((ushort)alf[t][j])) - qv[j];
                    ushort hi = f2bf(v);
                    ahf[t][j] = (short)hi;
                    alf[t][j] = (short)f2bf(v - bf2f(hi));
                }
            }
        }
    }

    // ---- final: exact residual chain (bit-identical to rounds 1/3) + out ----
    {
        const float* xb = x + (size_t)b * Dd * Tt + t_a;
        float* ob = out + (size_t)b * Dd * Tt + t_a;
#pragma unroll
        for (int t = 0; t < 16; ++t) {
            float xv[8], v[8];
#pragma unroll
            for (int j = 0; j < 8; ++j) {
                xv[j] = xb[(size_t)(16 * t + 8 * h + j) * Tt];
                v[j] = xv[j];
            }
            for (int lay = 0; lay < Ll; ++lay) {
                const float* qp = cb + ((size_t)lay * Kk + hist[lay][row32]) * Dd
                                  + 16 * t + 8 * h;
                float4 q0 = *(const float4*)qp;
                float4 q1 = *(const float4*)(qp + 4);
                v[0] -= q0.x; v[1] -= q0.y; v[2] -= q0.z; v[3] -= q0.w;
                v[4] -= q1.x; v[5] -= q1.y; v[6] -= q1.z; v[7] -= q1.w;
            }
#pragma unroll
            for (int j = 0; j < 8; ++j)
                ob[(size_t)(16 * t + 8 * h + j) * Tt] = xv[j] - v[j];
        }
    }
}

// ---------------------------------------------------------------------------
extern "C" void kernel_launch(void* const* d_in, const int* in_sizes, int n_in,
                              void* d_out, int out_size, void* d_ws, size_t ws_size,
                              hipStream_t stream) {
    const float* x  = (const float*)d_in[0];   // (B, D, T)
    const float* cb = (const float*)d_in[1];   // (L, K, D)
    float* out  = (float*)d_out;
    float* oidx = out + (size_t)Bb * Dd * Tt;  // (B, L, T) as fp32 values
    float*  wnbuf = (float*)d_ws;                          // 8192 floats
    ushort* spbuf = (ushort*)((char*)d_ws + 32768);        // split codebook, ~8.65 MB

    prep_kernel<<<Ll * Kk, 64, 0, stream>>>(cb, wnbuf, spbuf);
    rvq_kernel<<<(Bb * Tt) / VT, 256, 0, stream>>>(x, cb, wnbuf, spbuf, out, oidx);
}